// Round 1
// baseline (12209.332 us; speedup 1.0000x reference)
//
#include <hip/hip_runtime.h>
#include <math.h>

#define IN_CH 8
#define HID   64
#define EMB   32

// ---------------------------------------------------------------- scatter 1
// per edge: cnt[dst] += 1; sum1[dst][0..7] += x[src][0..7]
__global__ void scatter1_kernel(const int* __restrict__ ei, const float* __restrict__ x,
                                float* __restrict__ cnt, float* __restrict__ sum1, int E) {
    int e = blockIdx.x * blockDim.x + threadIdx.x;
    if (e >= E) return;
    int src = ei[e];
    int dst = ei[E + e];
    atomicAdd(cnt + dst, 1.0f);
    const float4* xs = (const float4*)(x + (size_t)src * IN_CH);
    float4 a = xs[0], b = xs[1];
    float* s = sum1 + (size_t)dst * IN_CH;
    atomicAdd(s + 0, a.x); atomicAdd(s + 1, a.y);
    atomicAdd(s + 2, a.z); atomicAdd(s + 3, a.w);
    atomicAdd(s + 4, b.x); atomicAdd(s + 5, b.y);
    atomicAdd(s + 6, b.z); atomicAdd(s + 7, b.w);
}

// ---------------------------------------------------------------- dense 1
// h = relu((sum1/max(cnt,1)) @ W1l + b1 + x @ W1r)    [N,64]
// block = 256 threads = 4 nodes x 64 output channels
__global__ void dense1_kernel(const float* __restrict__ x, const float* __restrict__ cnt,
                              const float* __restrict__ sum1,
                              const float* __restrict__ W1l, const float* __restrict__ b1,
                              const float* __restrict__ W1r,
                              float* __restrict__ h, int N) {
    __shared__ float sW1l[IN_CH * HID];
    __shared__ float sW1r[IN_CH * HID];
    __shared__ float sb1[HID];
    int t = threadIdx.x;
    for (int i = t; i < IN_CH * HID; i += 256) { sW1l[i] = W1l[i]; sW1r[i] = W1r[i]; }
    if (t < HID) sb1[t] = b1[t];
    __syncthreads();

    int node = blockIdx.x * 4 + (t >> 6);
    int j = t & 63;
    if (node >= N) return;

    float inv = 1.0f / fmaxf(cnt[node], 1.0f);
    float acc = sb1[j];
    #pragma unroll
    for (int k = 0; k < IN_CH; k++) {
        acc += sum1[(size_t)node * IN_CH + k] * inv * sW1l[k * HID + j]
             + x[(size_t)node * IN_CH + k] * sW1r[k * HID + j];
    }
    h[(size_t)node * HID + j] = fmaxf(acc, 0.0f);
}

// ---------------------------------------------------------------- scatter 2
// per edge: sum2[dst][0..63] += h[src][0..63]; 4 threads per edge, 16 ch each
__global__ void scatter2_kernel(const int* __restrict__ ei, const float* __restrict__ h,
                                float* __restrict__ sum2, int E) {
    int t = blockIdx.x * blockDim.x + threadIdx.x;
    int e = t >> 2;
    int q = t & 3;
    if (e >= E) return;
    int src = ei[e];
    int dst = ei[E + e];
    const float4* hs = (const float4*)(h + (size_t)src * HID + q * 16);
    float* s = sum2 + (size_t)dst * HID + q * 16;
    #pragma unroll
    for (int i = 0; i < 4; i++) {
        float4 v = hs[i];
        atomicAdd(s + i * 4 + 0, v.x);
        atomicAdd(s + i * 4 + 1, v.y);
        atomicAdd(s + i * 4 + 2, v.z);
        atomicAdd(s + i * 4 + 3, v.w);
    }
}

// ---------------------------------------------------------------- dense 2
// z = relu((sum2/max(cnt,1)) @ W2l + b2 + h @ W2r)    [N,32]
// block = 256 threads = 8 nodes x 32 output channels
__global__ void dense2_kernel(const float* __restrict__ h, const float* __restrict__ cnt,
                              const float* __restrict__ sum2,
                              const float* __restrict__ W2l, const float* __restrict__ b2,
                              const float* __restrict__ W2r,
                              float* __restrict__ z, int N) {
    __shared__ float sW2l[HID * EMB];
    __shared__ float sW2r[HID * EMB];
    __shared__ float sb2[EMB];
    int t = threadIdx.x;
    for (int i = t; i < HID * EMB; i += 256) { sW2l[i] = W2l[i]; sW2r[i] = W2r[i]; }
    if (t < EMB) sb2[t] = b2[t];
    __syncthreads();

    int node = blockIdx.x * 8 + (t >> 5);
    int j = t & 31;
    if (node >= N) return;

    float inv = 1.0f / fmaxf(cnt[node], 1.0f);
    float acc = sb2[j];
    #pragma unroll 8
    for (int k = 0; k < HID; k++) {
        acc += sum2[(size_t)node * HID + k] * inv * sW2l[k * EMB + j]
             + h[(size_t)node * HID + k] * sW2r[k * EMB + j];
    }
    z[(size_t)node * EMB + j] = fmaxf(acc, 0.0f);
}

// ---------------------------------------------------------------- head
// out = sigmoid(relu(z @ Wh1 + bh1) @ Wh2 + bh2)      [N]
__global__ void head_kernel(const float* __restrict__ z,
                            const float* __restrict__ Wh1, const float* __restrict__ bh1,
                            const float* __restrict__ Wh2, const float* __restrict__ bh2,
                            float* __restrict__ out, int N) {
    __shared__ float sW1[EMB * 16];
    __shared__ float sb1[16];
    __shared__ float sW2[16];
    __shared__ float sbias2;
    int t = threadIdx.x;
    for (int i = t; i < EMB * 16; i += blockDim.x) sW1[i] = Wh1[i];
    if (t < 16) { sb1[t] = bh1[t]; sW2[t] = Wh2[t]; }
    if (t == 0) sbias2 = bh2[0];
    __syncthreads();

    int n = blockIdx.x * blockDim.x + t;
    if (n >= N) return;

    float zv[EMB];
    const float4* zp = (const float4*)(z + (size_t)n * EMB);
    #pragma unroll
    for (int i = 0; i < EMB / 4; i++) {
        float4 v = zp[i];
        zv[4 * i + 0] = v.x; zv[4 * i + 1] = v.y;
        zv[4 * i + 2] = v.z; zv[4 * i + 3] = v.w;
    }
    float logit = sbias2;
    #pragma unroll
    for (int i = 0; i < 16; i++) {
        float acc = sb1[i];
        #pragma unroll
        for (int k = 0; k < EMB; k++) acc += zv[k] * sW1[k * 16 + i];
        logit += fmaxf(acc, 0.0f) * sW2[i];
    }
    out[n] = 1.0f / (1.0f + expf(-logit));
}

// ---------------------------------------------------------------- launch
extern "C" void kernel_launch(void* const* d_in, const int* in_sizes, int n_in,
                              void* d_out, int out_size, void* d_ws, size_t ws_size,
                              hipStream_t stream) {
    const float* x   = (const float*)d_in[0];
    const int*   ei  = (const int*)d_in[1];
    const float* W1l = (const float*)d_in[2];
    const float* b1  = (const float*)d_in[3];
    const float* W1r = (const float*)d_in[4];
    const float* W2l = (const float*)d_in[5];
    const float* b2  = (const float*)d_in[6];
    const float* W2r = (const float*)d_in[7];
    const float* Wh1 = (const float*)d_in[8];
    const float* bh1 = (const float*)d_in[9];
    const float* Wh2 = (const float*)d_in[10];
    const float* bh2 = (const float*)d_in[11];

    int N = in_sizes[0] / IN_CH;     // 100000
    int E = in_sizes[1] / 2;         // 3200000

    // workspace layout (floats): [cnt N][sum1 8N][sum2 64N][h 64N][z 32N]
    float* ws   = (float*)d_ws;
    float* cnt  = ws;
    float* sum1 = cnt + N;
    float* sum2 = sum1 + (size_t)N * IN_CH;
    float* h    = sum2 + (size_t)N * HID;
    float* z    = h + (size_t)N * HID;

    // zero the accumulators (cnt + sum1 + sum2 are contiguous)
    hipMemsetAsync(cnt, 0, sizeof(float) * (size_t)N * (1 + IN_CH + HID), stream);

    scatter1_kernel<<<(E + 255) / 256, 256, 0, stream>>>(ei, x, cnt, sum1, E);
    dense1_kernel<<<(N + 3) / 4, 256, 0, stream>>>(x, cnt, sum1, W1l, b1, W1r, h, N);
    scatter2_kernel<<<((E * 4) + 255) / 256, 256, 0, stream>>>(ei, h, sum2, E);
    dense2_kernel<<<(N + 7) / 8, 256, 0, stream>>>(h, cnt, sum2, W2l, b2, W2r, z, N);
    head_kernel<<<(N + 255) / 256, 256, 0, stream>>>(z, Wh1, bh1, Wh2, bh2, (float*)d_out, N);
}

// Round 2
// 861.852 us; speedup vs baseline: 14.1664x; 14.1664x over previous
//
#include <hip/hip_runtime.h>
#include <math.h>

#define IN_CH 8
#define HID   64
#define EMB   32

// ---------------------------------------------------------------- degree
__global__ void degree_kernel(const int* __restrict__ ei, int* __restrict__ deg, int E) {
    int e = blockIdx.x * blockDim.x + threadIdx.x;
    if (e < E) atomicAdd(&deg[ei[E + e]], 1);
}

// ---------------------------------------------------------------- scan (single block, 1024 thr)
__global__ __launch_bounds__(1024) void scan_kernel(const int* __restrict__ deg,
                                                    int* __restrict__ row_off, int N) {
    __shared__ int ssum[1024];
    int t = threadIdx.x;
    int chunk = (N + 1023) / 1024;
    int start = t * chunk;
    int end = min(start + chunk, N);
    int s = 0;
    for (int i = start; i < end; i++) s += deg[i];
    ssum[t] = s;
    __syncthreads();
    // Hillis-Steele inclusive scan over thread sums
    for (int off = 1; off < 1024; off <<= 1) {
        int v = (t >= off) ? ssum[t - off] : 0;
        __syncthreads();
        ssum[t] += v;
        __syncthreads();
    }
    int run = (t == 0) ? 0 : ssum[t - 1];
    for (int i = start; i < end; i++) { row_off[i] = run; run += deg[i]; }
    if (t == 1023) row_off[N] = run;   // = E (last thread's chunk covers tail)
}

// ---------------------------------------------------------------- CSR fill
__global__ void fill_kernel(const int* __restrict__ ei, const int* __restrict__ row_off,
                            int* __restrict__ cursor, int* __restrict__ csr, int E) {
    int e = blockIdx.x * blockDim.x + threadIdx.x;
    if (e >= E) return;
    int src = ei[e];
    int dst = ei[E + e];
    int pos = row_off[dst] + atomicAdd(&cursor[dst], 1);
    csr[pos] = src;
}

// ---------------------------------------------------------------- fused layer 1
// wave per node: 8 edge-groups x 8 channels gather x[src], xor-reduce, then
// 64 lanes compute h[node][lane] = relu(aggr@W1l + b1 + x@W1r)
__global__ __launch_bounds__(256) void fused1_kernel(
        const float* __restrict__ x, const int* __restrict__ row_off,
        const int* __restrict__ csr,
        const float* __restrict__ W1l, const float* __restrict__ b1,
        const float* __restrict__ W1r, float* __restrict__ h, int N) {
    __shared__ float sWl[IN_CH * HID];
    __shared__ float sWr[IN_CH * HID];
    __shared__ float sb[HID];
    int t = threadIdx.x;
    for (int i = t; i < IN_CH * HID; i += 256) { sWl[i] = W1l[i]; sWr[i] = W1r[i]; }
    if (t < HID) sb[t] = b1[t];
    __syncthreads();

    int lane = t & 63;
    int node = blockIdx.x * 4 + (t >> 6);
    if (node >= N) return;
    int r0 = row_off[node], r1 = row_off[node + 1];

    int g = lane >> 3;        // edge sub-group 0..7
    int c = lane & 7;         // channel 0..7
    float sum = 0.0f;
    for (int e = r0 + g; e < r1; e += 8)
        sum += x[(size_t)csr[e] * IN_CH + c];
    sum += __shfl_xor(sum, 8);
    sum += __shfl_xor(sum, 16);
    sum += __shfl_xor(sum, 32);
    // now lane l holds aggr-sum for channel l&7

    float inv = 1.0f / fmaxf((float)(r1 - r0), 1.0f);
    float xv = x[(size_t)node * IN_CH + c];   // lane k<8 holds x[node][k]

    float acc = sb[lane];
    #pragma unroll
    for (int k = 0; k < IN_CH; k++) {
        float ak = __shfl(sum, k) * inv;
        float xk = __shfl(xv, k);
        acc += ak * sWl[k * HID + lane] + xk * sWr[k * HID + lane];
    }
    h[(size_t)node * HID + lane] = fmaxf(acc, 0.0f);
}

// ---------------------------------------------------------------- fused layer 2 + head
// wave per node: lane=channel gather of h[src][lane] (coalesced 256B/neighbor),
// then dense2 (64->32) + head (32->16->1) via shfl broadcast, sigmoid write.
__global__ __launch_bounds__(256) void fused2_kernel(
        const float* __restrict__ h, const int* __restrict__ row_off,
        const int* __restrict__ csr,
        const float* __restrict__ W2l, const float* __restrict__ b2,
        const float* __restrict__ W2r,
        const float* __restrict__ Wh1, const float* __restrict__ bh1,
        const float* __restrict__ Wh2, const float* __restrict__ bh2,
        float* __restrict__ out, int N) {
    __shared__ float sWl[HID * EMB];
    __shared__ float sWr[HID * EMB];
    __shared__ float sb2[EMB];
    __shared__ float sH1[EMB * 16];
    __shared__ float sbh1[16];
    __shared__ float sH2[16];
    int t = threadIdx.x;
    for (int i = t; i < HID * EMB; i += 256) { sWl[i] = W2l[i]; sWr[i] = W2r[i]; }
    if (t < EMB) sb2[t] = b2[t];
    for (int i = t; i < EMB * 16; i += 256) sH1[i] = Wh1[i];
    if (t < 16) { sbh1[t] = bh1[t]; sH2[t] = Wh2[t]; }
    __syncthreads();

    int lane = t & 63;
    int node = blockIdx.x * 4 + (t >> 6);
    if (node >= N) return;
    int r0 = row_off[node], r1 = row_off[node + 1];

    float sum = 0.0f;
    int e = r0;
    for (; e + 4 <= r1; e += 4) {               // ILP-4 gather
        int s0 = csr[e], s1 = csr[e + 1], s2 = csr[e + 2], s3 = csr[e + 3];
        sum += h[(size_t)s0 * HID + lane];
        sum += h[(size_t)s1 * HID + lane];
        sum += h[(size_t)s2 * HID + lane];
        sum += h[(size_t)s3 * HID + lane];
    }
    for (; e < r1; e++) sum += h[(size_t)csr[e] * HID + lane];

    float inv = 1.0f / fmaxf((float)(r1 - r0), 1.0f);
    float aggr = sum * inv;                      // lane = channel
    float hv = h[(size_t)node * HID + lane];

    // dense2: j = lane&31 (upper half duplicates)
    int j = lane & 31;
    float acc = sb2[j];
    #pragma unroll
    for (int k = 0; k < HID; k++) {
        float ak = __shfl(aggr, k);
        float hk = __shfl(hv, k);
        acc += ak * sWl[k * EMB + j] + hk * sWr[k * EMB + j];
    }
    float z = fmaxf(acc, 0.0f);                  // z_j on lanes j and j+32

    // head hidden: i = lane&15
    int i = lane & 15;
    float hid = sbh1[i];
    #pragma unroll
    for (int k = 0; k < EMB; k++) {
        float zk = __shfl(z, k);                 // lane k<32 holds z_k
        hid += zk * sH1[k * 16 + i];
    }
    float part = fmaxf(hid, 0.0f) * sH2[i];
    part += __shfl_xor(part, 1);
    part += __shfl_xor(part, 2);
    part += __shfl_xor(part, 4);
    part += __shfl_xor(part, 8);

    if (lane == 0) {
        float logit = part + bh2[0];
        out[node] = 1.0f / (1.0f + expf(-logit));
    }
}

// ---------------------------------------------------------------- launch
extern "C" void kernel_launch(void* const* d_in, const int* in_sizes, int n_in,
                              void* d_out, int out_size, void* d_ws, size_t ws_size,
                              hipStream_t stream) {
    const float* x   = (const float*)d_in[0];
    const int*   ei  = (const int*)d_in[1];
    const float* W1l = (const float*)d_in[2];
    const float* b1  = (const float*)d_in[3];
    const float* W1r = (const float*)d_in[4];
    const float* W2l = (const float*)d_in[5];
    const float* b2  = (const float*)d_in[6];
    const float* W2r = (const float*)d_in[7];
    const float* Wh1 = (const float*)d_in[8];
    const float* bh1 = (const float*)d_in[9];
    const float* Wh2 = (const float*)d_in[10];
    const float* bh2 = (const float*)d_in[11];

    int N = in_sizes[0] / IN_CH;     // 100000
    int E = in_sizes[1] / 2;         // 3200000

    // workspace layout: ints [deg N][cursor N][row_off N+1][csr E], floats [h 64N]
    int* deg     = (int*)d_ws;
    int* cursor  = deg + N;
    int* row_off = cursor + N;
    int* csr     = row_off + (N + 1);
    float* h     = (float*)(csr + E);

    hipMemsetAsync(deg, 0, sizeof(int) * (size_t)N * 2, stream);   // deg + cursor

    degree_kernel<<<(E + 255) / 256, 256, 0, stream>>>(ei, deg, E);
    scan_kernel<<<1, 1024, 0, stream>>>(deg, row_off, N);
    fill_kernel<<<(E + 255) / 256, 256, 0, stream>>>(ei, row_off, cursor, csr, E);
    fused1_kernel<<<(N + 3) / 4, 256, 0, stream>>>(x, row_off, csr, W1l, b1, W1r, h, N);
    fused2_kernel<<<(N + 3) / 4, 256, 0, stream>>>(h, row_off, csr, W2l, b2, W2r,
                                                   Wh1, bh1, Wh2, bh2, (float*)d_out, N);
}

// Round 3
// 691.333 us; speedup vs baseline: 17.6606x; 1.2467x over previous
//
#include <hip/hip_runtime.h>
#include <math.h>

#define IN_CH 8
#define HID   64
#define EMB   32
#define SCAN_T 4096   // 16 blocks x 256

static __device__ __forceinline__ unsigned short f2bf(float f) {
    unsigned u = __float_as_uint(f);
    unsigned r = (u + 0x7fff + ((u >> 16) & 1)) >> 16;   // RNE
    return (unsigned short)r;
}
static __device__ __forceinline__ float bf2f(unsigned short s) {
    return __uint_as_float(((unsigned)s) << 16);
}

// ---------------------------------------------------------------- degree
__global__ void degree_kernel(const int* __restrict__ ei, int* __restrict__ deg, int E) {
    int e = blockIdx.x * blockDim.x + threadIdx.x;
    if (e < E) atomicAdd(&deg[ei[E + e]], 1);
}

// ---------------------------------------------------------------- scan phase 1: per-thread chunk sums
__global__ void scanA_kernel(const int* __restrict__ deg, int* __restrict__ tsum, int N) {
    int tid = blockIdx.x * blockDim.x + threadIdx.x;   // 0..SCAN_T-1
    int chunk = (N + SCAN_T - 1) / SCAN_T;
    int start = tid * chunk;
    int end = min(start + chunk, N);
    int s = 0;
    for (int i = start; i < end; i++) s += deg[i];
    tsum[tid] = s;
}

// ---------------------------------------------------------------- scan phase 2: 1 block scans SCAN_T sums
__global__ __launch_bounds__(256) void scanB_kernel(const int* __restrict__ tsum,
                                                    int* __restrict__ tpre) {
    __shared__ int bsum[256];
    int t = threadIdx.x;                 // each thread owns 16 consecutive tsum entries
    int s = 0;
    #pragma unroll
    for (int i = 0; i < 16; i++) s += tsum[t * 16 + i];
    bsum[t] = s;
    __syncthreads();
    for (int off = 1; off < 256; off <<= 1) {
        int v = (t >= off) ? bsum[t - off] : 0;
        __syncthreads();
        bsum[t] += v;
        __syncthreads();
    }
    int run = (t == 0) ? 0 : bsum[t - 1];
    #pragma unroll
    for (int i = 0; i < 16; i++) { tpre[t * 16 + i] = run; run += tsum[t * 16 + i]; }
}

// ---------------------------------------------------------------- scan phase 3: write row offsets
__global__ void scanC_kernel(const int* __restrict__ deg, const int* __restrict__ tpre,
                             int* __restrict__ row_off, int N) {
    int tid = blockIdx.x * blockDim.x + threadIdx.x;
    int chunk = (N + SCAN_T - 1) / SCAN_T;
    int start = tid * chunk;
    int end = min(start + chunk, N);
    int run = tpre[tid];
    for (int i = start; i < end; i++) { row_off[i] = run; run += deg[i]; }
    if (end == N && start < N) row_off[N] = run;
}

// ---------------------------------------------------------------- CSR fill
__global__ void fill_kernel(const int* __restrict__ ei, const int* __restrict__ row_off,
                            int* __restrict__ cursor, int* __restrict__ csr, int E) {
    int e = blockIdx.x * blockDim.x + threadIdx.x;
    if (e >= E) return;
    int src = ei[e];
    int dst = ei[E + e];
    int pos = row_off[dst] + atomicAdd(&cursor[dst], 1);
    csr[pos] = src;
}

// ---------------------------------------------------------------- fused layer 1 + dense2-precompute
// wave per node. Gather x[src] (8 lanes/neighbor), compute h[64] in registers
// (lane=channel), then p = h@W2l (bf16) and self = h@W2r + b2 (fp32).
// h never touches global memory.
__global__ __launch_bounds__(256) void fused1_kernel(
        const float* __restrict__ x, const int* __restrict__ row_off,
        const int* __restrict__ csr,
        const float* __restrict__ W1l, const float* __restrict__ b1,
        const float* __restrict__ W1r,
        const float* __restrict__ W2l, const float* __restrict__ b2,
        const float* __restrict__ W2r,
        unsigned* __restrict__ p32, float* __restrict__ selfb, int N) {
    __shared__ float sW1l[IN_CH * HID];
    __shared__ float sW1r[IN_CH * HID];
    __shared__ float sb1[HID];
    __shared__ float sW2l[HID * EMB];
    __shared__ float sW2r[HID * EMB];
    __shared__ float sb2[EMB];
    int t = threadIdx.x;
    for (int i = t; i < IN_CH * HID; i += 256) { sW1l[i] = W1l[i]; sW1r[i] = W1r[i]; }
    for (int i = t; i < HID * EMB; i += 256) { sW2l[i] = W2l[i]; sW2r[i] = W2r[i]; }
    if (t < HID) sb1[t] = b1[t];
    if (t < EMB) sb2[t] = b2[t];
    __syncthreads();

    int lane = t & 63;
    int node = blockIdx.x * 4 + (t >> 6);
    if (node >= N) return;
    int r0 = row_off[node], r1 = row_off[node + 1];

    // gather x over neighbors: 8 groups x 8 channels
    int g = lane >> 3;
    int c = lane & 7;
    float sum = 0.0f;
    for (int e = r0 + g; e < r1; e += 8)
        sum += x[(size_t)csr[e] * IN_CH + c];
    sum += __shfl_xor(sum, 8);
    sum += __shfl_xor(sum, 16);
    sum += __shfl_xor(sum, 32);

    float inv = 1.0f / fmaxf((float)(r1 - r0), 1.0f);
    float xv = x[(size_t)node * IN_CH + c];

    // h[lane] = relu(aggr@W1l + b1 + x@W1r)
    float acc = sb1[lane];
    #pragma unroll
    for (int k = 0; k < IN_CH; k++) {
        float ak = __shfl(sum, k) * inv;
        float xk = __shfl(xv, k);
        acc += ak * sW1l[k * HID + lane] + xk * sW1r[k * HID + lane];
    }
    float hreg = fmaxf(acc, 0.0f);   // lane = channel

    // p_j = h@W2l, self_j = h@W2r + b2   (j = lane&31)
    int j = lane & 31;
    float pacc = 0.0f, sacc = sb2[j];
    #pragma unroll
    for (int k = 0; k < HID; k++) {
        float hk = __shfl(hreg, k);
        pacc += hk * sW2l[k * EMB + j];
        sacc += hk * sW2r[k * EMB + j];
    }

    // pack p to bf16x2, lanes 0..15 store one uint each (64B/row)
    float lo = __shfl(pacc, (lane & 15) * 2);
    float hi = __shfl(pacc, (lane & 15) * 2 + 1);
    if (lane < 16)
        p32[(size_t)node * 16 + lane] = (unsigned)f2bf(lo) | ((unsigned)f2bf(hi) << 16);
    if (lane < 32)
        selfb[(size_t)node * EMB + lane] = sacc;
}

// ---------------------------------------------------------------- fused layer 2 + head
// wave per node: gather p[src] (bf16x2, 16 lanes/neighbor, 4 neighbors/instr),
// z = relu(mean + self), head MLP, sigmoid.
__global__ __launch_bounds__(256) void fused2_kernel(
        const unsigned* __restrict__ p32, const float* __restrict__ selfb,
        const int* __restrict__ row_off, const int* __restrict__ csr,
        const float* __restrict__ Wh1, const float* __restrict__ bh1,
        const float* __restrict__ Wh2, const float* __restrict__ bh2,
        float* __restrict__ out, int N) {
    __shared__ float sH1[EMB * 16];
    __shared__ float sbh1[16];
    __shared__ float sH2[16];
    int t = threadIdx.x;
    for (int i = t; i < EMB * 16; i += 256) sH1[i] = Wh1[i];
    if (t < 16) { sbh1[t] = bh1[t]; sH2[t] = Wh2[t]; }
    __syncthreads();

    int lane = t & 63;
    int node = blockIdx.x * 4 + (t >> 6);
    if (node >= N) return;
    int r0 = row_off[node], r1 = row_off[node + 1];

    // gather packed p: 4 groups x 16 channel-pairs
    int g = lane >> 4;          // 0..3
    int c2 = lane & 15;         // channel pair
    float ax = 0.0f, ay = 0.0f;
    for (int e = r0 + g; e < r1; e += 4) {
        unsigned u = p32[(size_t)csr[e] * 16 + c2];
        ax += bf2f((unsigned short)(u & 0xffff));
        ay += bf2f((unsigned short)(u >> 16));
    }
    ax += __shfl_xor(ax, 16); ay += __shfl_xor(ay, 16);
    ax += __shfl_xor(ax, 32); ay += __shfl_xor(ay, 32);
    // lane c2 now holds sums for channels (2*c2, 2*c2+1)

    float inv = 1.0f / fmaxf((float)(r1 - r0), 1.0f);

    int j = lane & 31;
    float sx = __shfl(ax, j >> 1);
    float sy = __shfl(ay, j >> 1);
    float aj = (j & 1) ? sy : sx;
    float z = fmaxf(aj * inv + selfb[(size_t)node * EMB + j], 0.0f);  // z_j on lanes j, j+32

    // head
    int i = lane & 15;
    float hid = sbh1[i];
    #pragma unroll
    for (int k = 0; k < EMB; k++) {
        float zk = __shfl(z, k);
        hid += zk * sH1[k * 16 + i];
    }
    float part = fmaxf(hid, 0.0f) * sH2[i];
    part += __shfl_xor(part, 1);
    part += __shfl_xor(part, 2);
    part += __shfl_xor(part, 4);
    part += __shfl_xor(part, 8);

    if (lane == 0) {
        float logit = part + bh2[0];
        out[node] = 1.0f / (1.0f + expf(-logit));
    }
}

// ---------------------------------------------------------------- launch
extern "C" void kernel_launch(void* const* d_in, const int* in_sizes, int n_in,
                              void* d_out, int out_size, void* d_ws, size_t ws_size,
                              hipStream_t stream) {
    const float* x   = (const float*)d_in[0];
    const int*   ei  = (const int*)d_in[1];
    const float* W1l = (const float*)d_in[2];
    const float* b1  = (const float*)d_in[3];
    const float* W1r = (const float*)d_in[4];
    const float* W2l = (const float*)d_in[5];
    const float* b2  = (const float*)d_in[6];
    const float* W2r = (const float*)d_in[7];
    const float* Wh1 = (const float*)d_in[8];
    const float* bh1 = (const float*)d_in[9];
    const float* Wh2 = (const float*)d_in[10];
    const float* bh2 = (const float*)d_in[11];

    int N = in_sizes[0] / IN_CH;     // 100000
    int E = in_sizes[1] / 2;         // 3200000

    // workspace: ints [deg N][cursor N][row_off N+1][tsum 4096][tpre 4096][csr E]
    //            then floats [self 32N], uints [p 16N]
    int* deg     = (int*)d_ws;
    int* cursor  = deg + N;
    int* row_off = cursor + N;
    int* tsum    = row_off + (N + 1);
    int* tpre    = tsum + SCAN_T;
    int* csr     = tpre + SCAN_T;
    float* selfb = (float*)(csr + E);
    unsigned* p32 = (unsigned*)(selfb + (size_t)N * EMB);

    hipMemsetAsync(deg, 0, sizeof(int) * (size_t)N * 2, stream);   // deg + cursor

    degree_kernel<<<(E + 255) / 256, 256, 0, stream>>>(ei, deg, E);
    scanA_kernel<<<SCAN_T / 256, 256, 0, stream>>>(deg, tsum, N);
    scanB_kernel<<<1, 256, 0, stream>>>(tsum, tpre);
    scanC_kernel<<<SCAN_T / 256, 256, 0, stream>>>(deg, tpre, row_off, N);
    fill_kernel<<<(E + 255) / 256, 256, 0, stream>>>(ei, row_off, cursor, csr, E);
    fused1_kernel<<<(N + 3) / 4, 256, 0, stream>>>(x, row_off, csr, W1l, b1, W1r,
                                                   W2l, b2, W2r, p32, selfb, N);
    fused2_kernel<<<(N + 3) / 4, 256, 0, stream>>>(p32, selfb, row_off, csr,
                                                   Wh1, bh1, Wh2, bh2, (float*)d_out, N);
}

// Round 4
// 416.727 us; speedup vs baseline: 29.2982x; 1.6590x over previous
//
#include <hip/hip_runtime.h>
#include <math.h>

#define IN_CH 8
#define HID   64
#define EMB   32
#define SCAN_T 4096     // 16 blocks x 256 for the histogram scan
#define HBLK  256       // blocks in hist/scatter phases
#define BW    128       // nodes per bucket (dst >> 7)
#define NBMAX 800       // max buckets supported (N <= 102400)

static __device__ __forceinline__ unsigned short f2bf(float f) {
    unsigned u = __float_as_uint(f);
    unsigned r = (u + 0x7fff + ((u >> 16) & 1)) >> 16;   // RNE
    return (unsigned short)r;
}
static __device__ __forceinline__ float bf2f(unsigned short s) {
    return __uint_as_float(((unsigned)s) << 16);
}

// ------------------------------------------------- pass A1: per-block bucket histogram
__global__ __launch_bounds__(256) void hist_kernel(const int* __restrict__ ei,
                                                   int* __restrict__ hist2, int E, int NB) {
    __shared__ int lh[NBMAX];
    int b = blockIdx.x, t = threadIdx.x;
    for (int i = t; i < NB; i += 256) lh[i] = 0;
    __syncthreads();
    int per = (E + gridDim.x - 1) / gridDim.x;
    int e0 = b * per, e1 = min(e0 + per, E);
    for (int e = e0 + t; e < e1; e += 256)
        atomicAdd(&lh[ei[E + e] >> 7], 1);
    __syncthreads();
    for (int i = t; i < NB; i += 256) hist2[b * NB + i] = lh[i];   // block-major, coalesced
}

// ------------------------------------------------- hist scan (bucket-major logical order)
// logical l = bucket*HBLK + block ; phys = block*NB + bucket
__global__ void hscanA_kernel(const int* __restrict__ hist2, int* __restrict__ tsum,
                              int M, int NB) {
    int tid = blockIdx.x * blockDim.x + threadIdx.x;
    int chunk = (M + SCAN_T - 1) / SCAN_T;
    int start = tid * chunk, end = min(start + chunk, M);
    int s = 0;
    for (int l = start; l < end; l++) s += hist2[(l & (HBLK - 1)) * NB + (l >> 8)];
    tsum[tid] = s;
}

__global__ __launch_bounds__(256) void hscanB_kernel(const int* __restrict__ tsum,
                                                     int* __restrict__ tpre) {
    __shared__ int bsum[256];
    int t = threadIdx.x;
    int s = 0;
    #pragma unroll
    for (int i = 0; i < 16; i++) s += tsum[t * 16 + i];
    bsum[t] = s;
    __syncthreads();
    for (int off = 1; off < 256; off <<= 1) {
        int v = (t >= off) ? bsum[t - off] : 0;
        __syncthreads();
        bsum[t] += v;
        __syncthreads();
    }
    int run = (t == 0) ? 0 : bsum[t - 1];
    #pragma unroll
    for (int i = 0; i < 16; i++) { tpre[t * 16 + i] = run; run += tsum[t * 16 + i]; }
}

__global__ void hscanC_kernel(const int* __restrict__ hist2, const int* __restrict__ tpre,
                              int* __restrict__ off2, int M, int NB) {
    int tid = blockIdx.x * blockDim.x + threadIdx.x;
    int chunk = (M + SCAN_T - 1) / SCAN_T;
    int start = tid * chunk, end = min(start + chunk, M);
    int run = tpre[tid];
    for (int l = start; l < end; l++) {
        int ph = (l & (HBLK - 1)) * NB + (l >> 8);
        off2[ph] = run;
        run += hist2[ph];
    }
}

// ------------------------------------------------- pass A2: scatter edges into bucket-segmented staging
// each (block,bucket) sub-segment is written only by this block, ascending -> full-line writes
__global__ __launch_bounds__(256) void scat_kernel(const int* __restrict__ ei,
                                                   const int* __restrict__ off2,
                                                   int2* __restrict__ staged, int E, int NB) {
    __shared__ int lcur[NBMAX];
    int b = blockIdx.x, t = threadIdx.x;
    for (int i = t; i < NB; i += 256) lcur[i] = off2[b * NB + i];
    __syncthreads();
    int per = (E + gridDim.x - 1) / gridDim.x;
    int e0 = b * per, e1 = min(e0 + per, E);
    for (int e = e0 + t; e < e1; e += 256) {
        int src = ei[e], dst = ei[E + e];
        int pos = atomicAdd(&lcur[dst >> 7], 1);
        staged[pos] = make_int2(src, dst);
    }
}

// ------------------------------------------------- pass B: per-bucket CSR build (block-local writes)
__global__ __launch_bounds__(256) void bucket_kernel(const int2* __restrict__ staged,
                                                     const int* __restrict__ off2,
                                                     int* __restrict__ row_off,
                                                     int* __restrict__ csr,
                                                     int N, int E, int NB) {
    __shared__ int cnt[BW], offx[BW], cur[BW];
    int b = blockIdx.x, t = threadIdx.x;
    int base = b * BW;
    int s0 = off2[b];                              // phys[block0][bucket b] == bucket start
    int s1 = (b + 1 < NB) ? off2[b + 1] : E;
    if (t < BW) cnt[t] = 0;
    __syncthreads();
    for (int e = s0 + t; e < s1; e += 256)
        atomicAdd(&cnt[staged[e].y - base], 1);
    __syncthreads();
    if (t < BW) offx[t] = cnt[t];
    __syncthreads();
    for (int off = 1; off < BW; off <<= 1) {       // inclusive Hillis-Steele over 128
        int v = (t >= off && t < BW) ? offx[t - off] : 0;
        __syncthreads();
        if (t < BW) offx[t] += v;
        __syncthreads();
    }
    if (t < BW) {
        int ex = offx[t] - cnt[t];                 // exclusive
        if (base + t < N) row_off[base + t] = s0 + ex;
        cnt[t] = ex;
        cur[t] = 0;
    }
    if (b == NB - 1 && t == 0) row_off[N] = s1;    // == E
    __syncthreads();
    for (int e = s0 + t; e < s1; e += 256) {
        int2 pr = staged[e];
        int li = pr.y - base;
        int pos = s0 + cnt[li] + atomicAdd(&cur[li], 1);
        csr[pos] = pr.x;
    }
}

// ---------------------------------------------------------------- fused layer 1 + dense2-precompute
__global__ __launch_bounds__(256) void fused1_kernel(
        const float* __restrict__ x, const int* __restrict__ row_off,
        const int* __restrict__ csr,
        const float* __restrict__ W1l, const float* __restrict__ b1,
        const float* __restrict__ W1r,
        const float* __restrict__ W2l, const float* __restrict__ b2,
        const float* __restrict__ W2r,
        unsigned* __restrict__ p32, float* __restrict__ selfb, int N) {
    __shared__ float sW1l[IN_CH * HID];
    __shared__ float sW1r[IN_CH * HID];
    __shared__ float sb1[HID];
    __shared__ float sW2l[HID * EMB];
    __shared__ float sW2r[HID * EMB];
    __shared__ float sb2[EMB];
    int t = threadIdx.x;
    for (int i = t; i < IN_CH * HID; i += 256) { sW1l[i] = W1l[i]; sW1r[i] = W1r[i]; }
    for (int i = t; i < HID * EMB; i += 256) { sW2l[i] = W2l[i]; sW2r[i] = W2r[i]; }
    if (t < HID) sb1[t] = b1[t];
    if (t < EMB) sb2[t] = b2[t];
    __syncthreads();

    int lane = t & 63;
    int node = blockIdx.x * 4 + (t >> 6);
    if (node >= N) return;
    int r0 = row_off[node], r1 = row_off[node + 1];

    int g = lane >> 3;
    int c = lane & 7;
    float sum = 0.0f;
    for (int e = r0 + g; e < r1; e += 8)
        sum += x[(size_t)csr[e] * IN_CH + c];
    sum += __shfl_xor(sum, 8);
    sum += __shfl_xor(sum, 16);
    sum += __shfl_xor(sum, 32);

    float inv = 1.0f / fmaxf((float)(r1 - r0), 1.0f);
    float xv = x[(size_t)node * IN_CH + c];

    float acc = sb1[lane];
    #pragma unroll
    for (int k = 0; k < IN_CH; k++) {
        float ak = __shfl(sum, k) * inv;
        float xk = __shfl(xv, k);
        acc += ak * sW1l[k * HID + lane] + xk * sW1r[k * HID + lane];
    }
    float hreg = fmaxf(acc, 0.0f);   // lane = channel

    int j = lane & 31;
    float pacc = 0.0f, sacc = sb2[j];
    #pragma unroll
    for (int k = 0; k < HID; k++) {
        float hk = __shfl(hreg, k);
        pacc += hk * sW2l[k * EMB + j];
        sacc += hk * sW2r[k * EMB + j];
    }

    float lo = __shfl(pacc, (lane & 15) * 2);
    float hi = __shfl(pacc, (lane & 15) * 2 + 1);
    if (lane < 16)
        p32[(size_t)node * 16 + lane] = (unsigned)f2bf(lo) | ((unsigned)f2bf(hi) << 16);
    if (lane < 32)
        selfb[(size_t)node * EMB + lane] = sacc;
}

// ---------------------------------------------------------------- fused layer 2 + head
__global__ __launch_bounds__(256) void fused2_kernel(
        const unsigned* __restrict__ p32, const float* __restrict__ selfb,
        const int* __restrict__ row_off, const int* __restrict__ csr,
        const float* __restrict__ Wh1, const float* __restrict__ bh1,
        const float* __restrict__ Wh2, const float* __restrict__ bh2,
        float* __restrict__ out, int N) {
    __shared__ float sH1[EMB * 16];
    __shared__ float sbh1[16];
    __shared__ float sH2[16];
    int t = threadIdx.x;
    for (int i = t; i < EMB * 16; i += 256) sH1[i] = Wh1[i];
    if (t < 16) { sbh1[t] = bh1[t]; sH2[t] = Wh2[t]; }
    __syncthreads();

    int lane = t & 63;
    int node = blockIdx.x * 4 + (t >> 6);
    if (node >= N) return;
    int r0 = row_off[node], r1 = row_off[node + 1];

    int g = lane >> 4;          // 0..3
    int c2 = lane & 15;         // channel pair
    float ax = 0.0f, ay = 0.0f;
    for (int e = r0 + g; e < r1; e += 4) {
        unsigned u = p32[(size_t)csr[e] * 16 + c2];
        ax += bf2f((unsigned short)(u & 0xffff));
        ay += bf2f((unsigned short)(u >> 16));
    }
    ax += __shfl_xor(ax, 16); ay += __shfl_xor(ay, 16);
    ax += __shfl_xor(ax, 32); ay += __shfl_xor(ay, 32);

    float inv = 1.0f / fmaxf((float)(r1 - r0), 1.0f);

    int j = lane & 31;
    float sx = __shfl(ax, j >> 1);
    float sy = __shfl(ay, j >> 1);
    float aj = (j & 1) ? sy : sx;
    float z = fmaxf(aj * inv + selfb[(size_t)node * EMB + j], 0.0f);

    int i = lane & 15;
    float hid = sbh1[i];
    #pragma unroll
    for (int k = 0; k < EMB; k++) {
        float zk = __shfl(z, k);
        hid += zk * sH1[k * 16 + i];
    }
    float part = fmaxf(hid, 0.0f) * sH2[i];
    part += __shfl_xor(part, 1);
    part += __shfl_xor(part, 2);
    part += __shfl_xor(part, 4);
    part += __shfl_xor(part, 8);

    if (lane == 0) {
        float logit = part + bh2[0];
        out[node] = 1.0f / (1.0f + expf(-logit));
    }
}

// ---------------------------------------------------------------- launch
extern "C" void kernel_launch(void* const* d_in, const int* in_sizes, int n_in,
                              void* d_out, int out_size, void* d_ws, size_t ws_size,
                              hipStream_t stream) {
    const float* x   = (const float*)d_in[0];
    const int*   ei  = (const int*)d_in[1];
    const float* W1l = (const float*)d_in[2];
    const float* b1  = (const float*)d_in[3];
    const float* W1r = (const float*)d_in[4];
    const float* W2l = (const float*)d_in[5];
    const float* b2  = (const float*)d_in[6];
    const float* W2r = (const float*)d_in[7];
    const float* Wh1 = (const float*)d_in[8];
    const float* bh1 = (const float*)d_in[9];
    const float* Wh2 = (const float*)d_in[10];
    const float* bh2 = (const float*)d_in[11];

    int N = in_sizes[0] / IN_CH;     // 100000
    int E = in_sizes[1] / 2;         // 3200000
    int NB = (N + BW - 1) / BW;      // 782 buckets (<= NBMAX)
    int M  = NB * HBLK;              // histogram cells

    // workspace layout:
    // [staged int2 E][hist2 M][off2 M][tsum 4096][tpre 4096][row_off N+1][csr E]
    // [selfb 32N f32][p32 16N u32]
    int2* staged  = (int2*)d_ws;
    int* hist2    = (int*)(staged + E);
    int* off2     = hist2 + M;
    int* tsum     = off2 + M;
    int* tpre     = tsum + SCAN_T;
    int* row_off  = tpre + SCAN_T;
    int* csr      = row_off + (N + 1);
    float* selfb  = (float*)(csr + E);
    unsigned* p32 = (unsigned*)(selfb + (size_t)N * EMB);

    hist_kernel  <<<HBLK, 256, 0, stream>>>(ei, hist2, E, NB);
    hscanA_kernel<<<SCAN_T / 256, 256, 0, stream>>>(hist2, tsum, M, NB);
    hscanB_kernel<<<1, 256, 0, stream>>>(tsum, tpre);
    hscanC_kernel<<<SCAN_T / 256, 256, 0, stream>>>(hist2, tpre, off2, M, NB);
    scat_kernel  <<<HBLK, 256, 0, stream>>>(ei, off2, staged, E, NB);
    bucket_kernel<<<NB, 256, 0, stream>>>(staged, off2, row_off, csr, N, E, NB);
    fused1_kernel<<<(N + 3) / 4, 256, 0, stream>>>(x, row_off, csr, W1l, b1, W1r,
                                                   W2l, b2, W2r, p32, selfb, N);
    fused2_kernel<<<(N + 3) / 4, 256, 0, stream>>>(p32, selfb, row_off, csr,
                                                   Wh1, bh1, Wh2, bh2, (float*)d_out, N);
}

// Round 5
// 249.500 us; speedup vs baseline: 48.9352x; 1.6702x over previous
//
#include <hip/hip_runtime.h>
#include <math.h>

#define IN_CH 8
#define HID   64
#define EMB   32
#define SCAN_T 4096     // 16 blocks x 256 for the histogram scan
#define HBLK  256       // blocks in hist/scatter phases
#define BW    128       // nodes per bucket (dst >> 7)
#define NBMAX 800       // max buckets supported (N <= 102400)

static __device__ __forceinline__ unsigned short f2bf(float f) {
    unsigned u = __float_as_uint(f);
    unsigned r = (u + 0x7fff + ((u >> 16) & 1)) >> 16;   // RNE
    return (unsigned short)r;
}
static __device__ __forceinline__ float bf2f(unsigned short s) {
    return __uint_as_float(((unsigned)s) << 16);
}

// ------------------------------------------------- pass A1: per-block bucket histogram
__global__ __launch_bounds__(256) void hist_kernel(const int* __restrict__ ei,
                                                   int* __restrict__ hist2, int E, int NB) {
    __shared__ int lh[NBMAX];
    int b = blockIdx.x, t = threadIdx.x;
    for (int i = t; i < NB; i += 256) lh[i] = 0;
    __syncthreads();
    int per = (E + gridDim.x - 1) / gridDim.x;
    int e0 = b * per, e1 = min(e0 + per, E);
    for (int e = e0 + t; e < e1; e += 256)
        atomicAdd(&lh[ei[E + e] >> 7], 1);
    __syncthreads();
    for (int i = t; i < NB; i += 256) hist2[b * NB + i] = lh[i];
}

// ------------------------------------------------- hist scan (bucket-major logical order)
__global__ void hscanA_kernel(const int* __restrict__ hist2, int* __restrict__ tsum,
                              int M, int NB) {
    int tid = blockIdx.x * blockDim.x + threadIdx.x;
    int chunk = (M + SCAN_T - 1) / SCAN_T;
    int start = tid * chunk, end = min(start + chunk, M);
    int s = 0;
    for (int l = start; l < end; l++) s += hist2[(l & (HBLK - 1)) * NB + (l >> 8)];
    tsum[tid] = s;
}

__global__ __launch_bounds__(256) void hscanB_kernel(const int* __restrict__ tsum,
                                                     int* __restrict__ tpre) {
    __shared__ int bsum[256];
    int t = threadIdx.x;
    int s = 0;
    #pragma unroll
    for (int i = 0; i < 16; i++) s += tsum[t * 16 + i];
    bsum[t] = s;
    __syncthreads();
    for (int off = 1; off < 256; off <<= 1) {
        int v = (t >= off) ? bsum[t - off] : 0;
        __syncthreads();
        bsum[t] += v;
        __syncthreads();
    }
    int run = (t == 0) ? 0 : bsum[t - 1];
    #pragma unroll
    for (int i = 0; i < 16; i++) { tpre[t * 16 + i] = run; run += tsum[t * 16 + i]; }
}

__global__ void hscanC_kernel(const int* __restrict__ hist2, const int* __restrict__ tpre,
                              int* __restrict__ off2, int M, int NB) {
    int tid = blockIdx.x * blockDim.x + threadIdx.x;
    int chunk = (M + SCAN_T - 1) / SCAN_T;
    int start = tid * chunk, end = min(start + chunk, M);
    int run = tpre[tid];
    for (int l = start; l < end; l++) {
        int ph = (l & (HBLK - 1)) * NB + (l >> 8);
        off2[ph] = run;
        run += hist2[ph];
    }
}

// ------------------------------------------------- pass A2: scatter edges (packed src|li)
__global__ __launch_bounds__(256) void scat_kernel(const int* __restrict__ ei,
                                                   const int* __restrict__ off2,
                                                   int* __restrict__ staged, int E, int NB) {
    __shared__ int lcur[NBMAX];
    int b = blockIdx.x, t = threadIdx.x;
    for (int i = t; i < NB; i += 256) lcur[i] = off2[b * NB + i];
    __syncthreads();
    int per = (E + gridDim.x - 1) / gridDim.x;
    int e0 = b * per, e1 = min(e0 + per, E);
    for (int e = e0 + t; e < e1; e += 256) {
        int src = ei[e], dst = ei[E + e];
        int pos = atomicAdd(&lcur[dst >> 7], 1);
        staged[pos] = src | ((dst & (BW - 1)) << 17);   // src<2^17, li<128
    }
}

// ------------------------------------------------- pass B: per-bucket CSR build
__global__ __launch_bounds__(256) void bucket_kernel(const int* __restrict__ staged,
                                                     const int* __restrict__ off2,
                                                     int* __restrict__ row_off,
                                                     int* __restrict__ csr,
                                                     int N, int E, int NB) {
    __shared__ int cnt[BW], offx[BW], cur[BW];
    int b = blockIdx.x, t = threadIdx.x;
    int base = b * BW;
    int s0 = off2[b];
    int s1 = (b + 1 < NB) ? off2[b + 1] : E;
    if (t < BW) cnt[t] = 0;
    __syncthreads();
    for (int e = s0 + t; e < s1; e += 256)
        atomicAdd(&cnt[staged[e] >> 17], 1);
    __syncthreads();
    if (t < BW) offx[t] = cnt[t];
    __syncthreads();
    for (int off = 1; off < BW; off <<= 1) {
        int v = (t >= off && t < BW) ? offx[t - off] : 0;
        __syncthreads();
        if (t < BW) offx[t] += v;
        __syncthreads();
    }
    if (t < BW) {
        int ex = offx[t] - cnt[t];
        if (base + t < N) row_off[base + t] = s0 + ex;
        cnt[t] = ex;
        cur[t] = 0;
    }
    if (b == NB - 1 && t == 0) row_off[N] = s1;
    __syncthreads();
    for (int e = s0 + t; e < s1; e += 256) {
        int v = staged[e];
        int li = v >> 17;
        int pos = s0 + cnt[li] + atomicAdd(&cur[li], 1);
        csr[pos] = v & 0x1FFFF;
    }
}

// ------------------------------------------------- gather1: mean of x over neighbors
// wave per node; csr staged in registers + shfl-broadcast; float2 lanes ->
// 16 neighbor-rows in flight per wave.
__global__ __launch_bounds__(256) void gather1_kernel(
        const float* __restrict__ x, const int* __restrict__ row_off,
        const int* __restrict__ csr, float* __restrict__ aggr, int N) {
    int t = threadIdx.x;
    int lane = t & 63;
    int node = blockIdx.x * 4 + (t >> 6);
    if (node >= N) return;
    int r0 = row_off[node], r1 = row_off[node + 1];
    int deg = r1 - r0;

    int my = (r0 + lane < r1) ? csr[r0 + lane] : 0;
    int g = lane >> 2;        // 16 groups
    int q = lane & 3;         // float2 slot -> channels 2q, 2q+1
    float ax = 0.0f, ay = 0.0f;
    int lim = min(deg, 64);
    int i = g;
    for (; i + 16 < lim; i += 32) {           // unroll 2
        int s0 = __shfl(my, i), s1 = __shfl(my, i + 16);
        float2 v0 = *(const float2*)(x + (size_t)s0 * IN_CH + q * 2);
        float2 v1 = *(const float2*)(x + (size_t)s1 * IN_CH + q * 2);
        ax += v0.x + v1.x; ay += v0.y + v1.y;
    }
    if (i < lim) {
        int s0 = __shfl(my, i);
        float2 v0 = *(const float2*)(x + (size_t)s0 * IN_CH + q * 2);
        ax += v0.x; ay += v0.y;
    }
    for (int e = r0 + 64 + g; e < r1; e += 16) {   // rare deg>64 tail
        int s0 = csr[e];
        float2 v0 = *(const float2*)(x + (size_t)s0 * IN_CH + q * 2);
        ax += v0.x; ay += v0.y;
    }
    ax += __shfl_xor(ax, 4);  ay += __shfl_xor(ay, 4);
    ax += __shfl_xor(ax, 8);  ay += __shfl_xor(ay, 8);
    ax += __shfl_xor(ax, 16); ay += __shfl_xor(ay, 16);
    ax += __shfl_xor(ax, 32); ay += __shfl_xor(ay, 32);

    float inv = 1.0f / fmaxf((float)deg, 1.0f);
    if (lane < 4)
        ((float2*)(aggr + (size_t)node * IN_CH))[q] = make_float2(ax * inv, ay * inv);
}

// ------------------------------------------------- dense1b: node-per-thread dense chain
// h = relu(aggr@W1l + b1 + x@W1r); p = h@W2l (bf16); self = h@W2r + b2.
// All weight reads are wave-uniform -> s_load via constant cache. No LDS/shfl.
__global__ __launch_bounds__(128) void dense1b_kernel(
        const float* __restrict__ x, const float* __restrict__ aggr,
        const float* __restrict__ W1l, const float* __restrict__ b1,
        const float* __restrict__ W1r,
        const float* __restrict__ W2l, const float* __restrict__ b2,
        const float* __restrict__ W2r,
        unsigned* __restrict__ p32, float* __restrict__ selfb, int N) {
    int n = blockIdx.x * 128 + threadIdx.x;
    if (n >= N) return;

    float av[IN_CH], xv[IN_CH];
    {
        float4 a0 = ((const float4*)(aggr + (size_t)n * IN_CH))[0];
        float4 a1 = ((const float4*)(aggr + (size_t)n * IN_CH))[1];
        av[0] = a0.x; av[1] = a0.y; av[2] = a0.z; av[3] = a0.w;
        av[4] = a1.x; av[5] = a1.y; av[6] = a1.z; av[7] = a1.w;
        float4 b0 = ((const float4*)(x + (size_t)n * IN_CH))[0];
        float4 b1v = ((const float4*)(x + (size_t)n * IN_CH))[1];
        xv[0] = b0.x; xv[1] = b0.y; xv[2] = b0.z; xv[3] = b0.w;
        xv[4] = b1v.x; xv[5] = b1v.y; xv[6] = b1v.z; xv[7] = b1v.w;
    }

    float pacc[EMB], sacc[EMB];
    #pragma unroll
    for (int j = 0; j < EMB; j++) { pacc[j] = 0.0f; sacc[j] = b2[j]; }

    for (int k = 0; k < HID; k++) {
        float hk = b1[k];
        #pragma unroll
        for (int c = 0; c < IN_CH; c++)
            hk += av[c] * W1l[c * HID + k] + xv[c] * W1r[c * HID + k];
        hk = fmaxf(hk, 0.0f);
        const float* wl = W2l + k * EMB;
        const float* wr = W2r + k * EMB;
        #pragma unroll
        for (int j = 0; j < EMB; j++) {
            pacc[j] += hk * wl[j];
            sacc[j] += hk * wr[j];
        }
    }

    unsigned up[16];
    #pragma unroll
    for (int m = 0; m < 16; m++)
        up[m] = (unsigned)f2bf(pacc[2 * m]) | ((unsigned)f2bf(pacc[2 * m + 1]) << 16);
    uint4* pp = (uint4*)(p32 + (size_t)n * 16);
    pp[0] = make_uint4(up[0], up[1], up[2], up[3]);
    pp[1] = make_uint4(up[4], up[5], up[6], up[7]);
    pp[2] = make_uint4(up[8], up[9], up[10], up[11]);
    pp[3] = make_uint4(up[12], up[13], up[14], up[15]);
    float4* sp = (float4*)(selfb + (size_t)n * EMB);
    #pragma unroll
    for (int m = 0; m < 8; m++)
        sp[m] = make_float4(sacc[4 * m], sacc[4 * m + 1], sacc[4 * m + 2], sacc[4 * m + 3]);
}

// ---------------------------------------------------------------- fused layer 2 + head
__global__ __launch_bounds__(256) void fused2_kernel(
        const unsigned* __restrict__ p32, const float* __restrict__ selfb,
        const int* __restrict__ row_off, const int* __restrict__ csr,
        const float* __restrict__ Wh1, const float* __restrict__ bh1,
        const float* __restrict__ Wh2, const float* __restrict__ bh2,
        float* __restrict__ out, int N) {
    __shared__ float sH1[EMB * 16];
    __shared__ float sbh1[16];
    __shared__ float sH2[16];
    int t = threadIdx.x;
    for (int i = t; i < EMB * 16; i += 256) sH1[i] = Wh1[i];
    if (t < 16) { sbh1[t] = bh1[t]; sH2[t] = Wh2[t]; }
    __syncthreads();

    int lane = t & 63;
    int node = blockIdx.x * 4 + (t >> 6);
    if (node >= N) return;
    int r0 = row_off[node], r1 = row_off[node + 1];
    int deg = r1 - r0;

    int my = (r0 + lane < r1) ? csr[r0 + lane] : 0;
    int g = lane >> 4;          // 4 groups
    int c2 = lane & 15;         // channel pair
    float ax = 0.0f, ay = 0.0f;
    int lim = min(deg, 64);
    int i = g;
    for (; i + 12 < lim; i += 16) {            // unroll 4
        int s0 = __shfl(my, i),     s1 = __shfl(my, i + 4);
        int s2 = __shfl(my, i + 8), s3 = __shfl(my, i + 12);
        unsigned u0 = p32[(size_t)s0 * 16 + c2];
        unsigned u1 = p32[(size_t)s1 * 16 + c2];
        unsigned u2 = p32[(size_t)s2 * 16 + c2];
        unsigned u3 = p32[(size_t)s3 * 16 + c2];
        ax += bf2f((unsigned short)(u0 & 0xffff)) + bf2f((unsigned short)(u1 & 0xffff))
            + bf2f((unsigned short)(u2 & 0xffff)) + bf2f((unsigned short)(u3 & 0xffff));
        ay += bf2f((unsigned short)(u0 >> 16)) + bf2f((unsigned short)(u1 >> 16))
            + bf2f((unsigned short)(u2 >> 16)) + bf2f((unsigned short)(u3 >> 16));
    }
    for (; i < lim; i += 4) {
        unsigned u = p32[(size_t)__shfl(my, i) * 16 + c2];
        ax += bf2f((unsigned short)(u & 0xffff));
        ay += bf2f((unsigned short)(u >> 16));
    }
    for (int e = r0 + 64 + g; e < r1; e += 4) {   // rare deg>64 tail
        unsigned u = p32[(size_t)csr[e] * 16 + c2];
        ax += bf2f((unsigned short)(u & 0xffff));
        ay += bf2f((unsigned short)(u >> 16));
    }
    ax += __shfl_xor(ax, 16); ay += __shfl_xor(ay, 16);
    ax += __shfl_xor(ax, 32); ay += __shfl_xor(ay, 32);

    float inv = 1.0f / fmaxf((float)deg, 1.0f);

    int j = lane & 31;
    float sx = __shfl(ax, j >> 1);
    float sy = __shfl(ay, j >> 1);
    float aj = (j & 1) ? sy : sx;
    float z = fmaxf(aj * inv + selfb[(size_t)node * EMB + j], 0.0f);

    int i2 = lane & 15;
    float hid = sbh1[i2];
    #pragma unroll
    for (int k = 0; k < EMB; k++) {
        float zk = __shfl(z, k);
        hid += zk * sH1[k * 16 + i2];
    }
    float part = fmaxf(hid, 0.0f) * sH2[i2];
    part += __shfl_xor(part, 1);
    part += __shfl_xor(part, 2);
    part += __shfl_xor(part, 4);
    part += __shfl_xor(part, 8);

    if (lane == 0) {
        float logit = part + bh2[0];
        out[node] = 1.0f / (1.0f + expf(-logit));
    }
}

// ---------------------------------------------------------------- launch
extern "C" void kernel_launch(void* const* d_in, const int* in_sizes, int n_in,
                              void* d_out, int out_size, void* d_ws, size_t ws_size,
                              hipStream_t stream) {
    const float* x   = (const float*)d_in[0];
    const int*   ei  = (const int*)d_in[1];
    const float* W1l = (const float*)d_in[2];
    const float* b1  = (const float*)d_in[3];
    const float* W1r = (const float*)d_in[4];
    const float* W2l = (const float*)d_in[5];
    const float* b2  = (const float*)d_in[6];
    const float* W2r = (const float*)d_in[7];
    const float* Wh1 = (const float*)d_in[8];
    const float* bh1 = (const float*)d_in[9];
    const float* Wh2 = (const float*)d_in[10];
    const float* bh2 = (const float*)d_in[11];

    int N = in_sizes[0] / IN_CH;     // 100000
    int E = in_sizes[1] / 2;         // 3200000
    int NB = (N + BW - 1) / BW;      // 782 buckets
    int M  = NB * HBLK;

    // workspace layout:
    // [staged int E][hist2 M][off2 M][tsum 4096][tpre 4096][row_off N+1][csr E]
    // [aggr 8N f32][selfb 32N f32][p32 16N u32]
    int* staged   = (int*)d_ws;
    int* hist2    = staged + E;
    int* off2     = hist2 + M;
    int* tsum     = off2 + M;
    int* tpre     = tsum + SCAN_T;
    int* row_off  = tpre + SCAN_T;
    int* csr      = row_off + (N + 1);
    float* aggr   = (float*)(csr + E);
    float* selfb  = aggr + (size_t)N * IN_CH;
    unsigned* p32 = (unsigned*)(selfb + (size_t)N * EMB);

    hist_kernel   <<<HBLK, 256, 0, stream>>>(ei, hist2, E, NB);
    hscanA_kernel <<<SCAN_T / 256, 256, 0, stream>>>(hist2, tsum, M, NB);
    hscanB_kernel <<<1, 256, 0, stream>>>(tsum, tpre);
    hscanC_kernel <<<SCAN_T / 256, 256, 0, stream>>>(hist2, tpre, off2, M, NB);
    scat_kernel   <<<HBLK, 256, 0, stream>>>(ei, off2, staged, E, NB);
    bucket_kernel <<<NB, 256, 0, stream>>>(staged, off2, row_off, csr, N, E, NB);
    gather1_kernel<<<(N + 3) / 4, 256, 0, stream>>>(x, row_off, csr, aggr, N);
    dense1b_kernel<<<(N + 127) / 128, 128, 0, stream>>>(x, aggr, W1l, b1, W1r,
                                                        W2l, b2, W2r, p32, selfb, N);
    fused2_kernel <<<(N + 3) / 4, 256, 0, stream>>>(p32, selfb, row_off, csr,
                                                    Wh1, bh1, Wh2, bh2, (float*)d_out, N);
}